// Round 9
// baseline (2111.280 us; speedup 1.0000x reference)
//
#include <hip/hip_runtime.h>

// Problem constants (fixed by the reference).
#define TSTEPS 256
#define NNODE  100000
#define NEDGE  8192

constexpr float MU_P  = 0.1f;
constexpr float MU_M  = 0.05f;
constexpr float RHO_  = 16.0f;
constexpr float CLO   = 1e-5f;
constexpr float CHI   = 1.0f - 1e-5f;
constexpr float SCALE = 1048576.0f;          // 2^20 fixed-point for delta
constexpr float INVSC = 1.0f / 1048576.0f;

// f32 sentinel for "not written at this timestep": real X values are positive
// finite floats, so the bit pattern 0xFFFFFFFF (-NaN) can never occur.
#define SENT32 0xFFFFFFFFu

__device__ __forceinline__ float sigm(float x) {
  return 1.0f / (1.0f + __expf(-x));
}
__device__ __forceinline__ float x0_of(const float* logit, int n) {
  return fminf(fmaxf(sigm(logit[n]), CLO), CHI);
}
__device__ __forceinline__ int edge_at(const int* __restrict__ arr, int idx,
                                       int is64) {
  if (is64) return (int)((const long long*)arr)[idx];
  return arr[idx];
}

// ---------------------------------------------------------------------------
// k_detect: int32 vs int64 materialization of u/v (runtime-proof either way).
// ---------------------------------------------------------------------------
__global__ void k_detect(const int* __restrict__ u, const int* __restrict__ v,
                         unsigned* __restrict__ dflags) {
  if (threadIdx.x != 0 || blockIdx.x != 0) return;
  const unsigned* a = (const unsigned*)u;
  const unsigned* b = (const unsigned*)v;
  bool i64 = true;
  for (int k = 1; k < 128; k += 2) i64 = i64 && (a[k] == 0u) && (b[k] == 0u);
  dflags[0] = i64 ? 1u : 0u;
}

// ---------------------------------------------------------------------------
// k_init: xs = clip(sigmoid(logit)) f32 working state; delta/claim zeroed;
// output X row 0 = sigmoid(logit) UNCLIPPED f32 (matches reference X0);
// X rows 1..T-1 = f32 sentinel. Re-runs every call -> deterministic replays.
// ---------------------------------------------------------------------------
__global__ void k_init(const float* __restrict__ logit,
                       float* __restrict__ xs,
                       unsigned* __restrict__ delta,
                       unsigned* __restrict__ claim,
                       float* __restrict__ outX) {
  const int i = blockIdx.x * blockDim.x + threadIdx.x;
  const int stride = gridDim.x * blockDim.x;

  for (int n = i; n < NNODE; n += stride) {
    xs[n]    = x0_of(logit, n);          // clip is a no-op for sigmoid(normal)
    delta[n] = 0u;
    claim[n] = 0u;
    outX[n]  = sigm(logit[n]);           // row 0, unclipped, f32
  }
  unsigned* outX32 = (unsigned*)outX;
  const int total = TSTEPS * NNODE;
  for (int w = NNODE + i; w < total; w += stride) outX32[w] = SENT32;
}

// ---------------------------------------------------------------------------
// kG (one dispatch per timestep t): per edge e of row t:
//   gather xs[u], xs[v] (fresh via dispatch boundary), kappa row t in f32,
//   if t < T-1: fixed-point atomicAdd of +-w*d into delta (u32, exact,
//   commutative -> bit-deterministic).
// ---------------------------------------------------------------------------
__global__ void kG(const int* __restrict__ u, const int* __restrict__ v,
                   const float* __restrict__ sp, const float* __restrict__ sm,
                   const float* __restrict__ theta,
                   const float* __restrict__ xs,
                   unsigned* __restrict__ delta,
                   float* __restrict__ outKp,
                   float* __restrict__ outKm,
                   const unsigned* __restrict__ dflags,
                   int t) {
  const int i = blockIdx.x * blockDim.x + threadIdx.x;   // 0..NEDGE-1
  const int e = t * NEDGE + i;
  const int is64 = (int)dflags[0];

  const int un = edge_at(u, e, is64);
  const int vn = edge_at(v, e, is64);
  const float xu = xs[un];
  const float xv = xs[vn];
  const float d  = xv - xu;                 // = -(Xu - Xv); |d| drives kappa
  const float ad = fabsf(d);

  const float epsp = sigm(theta[0]) * 0.5f;
  const float epsm = 0.5f + sigm(theta[1]) * 0.5f;
  outKp[e] = sigm(RHO_ * (epsp - ad));      // f32 store
  outKm[e] = sigm(RHO_ * (ad - epsm));      // f32 store

  if (t < TSTEPS - 1) {
    const float w  = MU_P * sp[e] - MU_M * sm[e];
    const int   iv = __float2int_rn(w * d * SCALE);
    atomicAdd(&delta[un], (unsigned)iv);
    atomicAdd(&delta[vn], (unsigned)(-iv));
  }
}

// ---------------------------------------------------------------------------
// kA (one dispatch per timestep t): per endpoint slot s of row t:
//   claim-dedup (one owner per touched node, epoch t+1);
//   owner: acc = exch(delta,0); nv = clip(xs + acc/2^20); xs = nv;
//          scatter f32 nv into X row t+1 (sentinel-prefilled).
// ---------------------------------------------------------------------------
__global__ void kA(const int* __restrict__ u, const int* __restrict__ v,
                   float* __restrict__ xs,
                   unsigned* __restrict__ delta,
                   unsigned* __restrict__ claim,
                   float* __restrict__ outX,
                   const unsigned* __restrict__ dflags,
                   int t) {
  const int s = blockIdx.x * blockDim.x + threadIdx.x;   // 0..2*NEDGE-1
  const int is64 = (int)dflags[0];
  const int node = (s < NEDGE) ? edge_at(u, t * NEDGE + s, is64)
                               : edge_at(v, t * NEDGE + s - NEDGE, is64);

  const unsigned epoch = (unsigned)(t + 1);
  if (atomicExch(&claim[node], epoch) != epoch) {   // unique owner
    const int acc = (int)atomicExch(&delta[node], 0u);
    const float nv = fminf(fmaxf(xs[node] + (float)acc * INVSC, CLO), CHI);
    xs[node] = nv;
    outX[(size_t)(t + 1) * NNODE + node] = nv;      // f32 store
  }
}

// ---------------------------------------------------------------------------
// k_fill: resolve sentinels by fill-forward. Per-node carry across t;
// coalesced 4B accesses (consecutive threads -> consecutive nodes).
// ---------------------------------------------------------------------------
__global__ void k_fill(const float* __restrict__ logit,
                       unsigned* __restrict__ outX32) {
  const int n = blockIdx.x * blockDim.x + threadIdx.x;
  if (n >= NNODE) return;
  // rows t>=1 for never-touched nodes are clip(X0)
  unsigned carry = __float_as_uint(x0_of(logit, n));
  for (int t = 1; t < TSTEPS; ++t) {
    const size_t idx = (size_t)t * NNODE + n;
    const unsigned w = outX32[idx];
    if (w == SENT32) outX32[idx] = carry;
    else             carry = w;
  }
}

// ---------------------------------------------------------------------------
// kDiag: forced host-probe failure encoding only (layout/ws sanity).
// ---------------------------------------------------------------------------
__global__ void kDiag(float* __restrict__ outX, int b0, int b1) {
  if (threadIdx.x != 0 || blockIdx.x != 0) return;
  outX[0] = (float)(2048 + 1024 * b0 + 512 * b1);
}

// ---------------------------------------------------------------------------
extern "C" void kernel_launch(void* const* d_in, const int* in_sizes, int n_in,
                              void* d_out, int out_size, void* d_ws, size_t ws_size,
                              hipStream_t stream) {
  const float* logit = (const float*)d_in[0];
  const float* theta = (const float*)d_in[1];
  const int*   u     = (const int*)d_in[2];
  const int*   v     = (const int*)d_in[3];
  const float* sp    = (const float*)d_in[4];
  const float* sm    = (const float*)d_in[5];

  float* outX  = (float*)d_out;                         // [T, N] f32
  float* outKp = outX + (size_t)TSTEPS * NNODE;         // [T, E] f32
  float* outKm = outKp + (size_t)TSTEPS * NEDGE;        // [T, E] f32

  const int b0 = (n_in == 6 &&
                  in_sizes[0] == NNODE && in_sizes[1] == 2 &&
                  in_sizes[2] == TSTEPS * NEDGE && in_sizes[3] == TSTEPS * NEDGE &&
                  in_sizes[4] == TSTEPS * NEDGE && in_sizes[5] == TSTEPS * NEDGE) ? 1 : 0;
  const int b1 = (ws_size >= 1250000) ? 1 : 0;
  if (!b0 || !b1) {
    kDiag<<<1, 64, 0, stream>>>(outX, b0, b1);
    return;
  }

  // workspace: xs (N f32) | delta (N u32) | claim (N u32) | dflags (8 u32)
  char* ws = (char*)d_ws;
  float*    xs     = (float*)ws;
  unsigned* delta  = (unsigned*)(ws + (size_t)NNODE * 4);
  unsigned* claim  = (unsigned*)(ws + (size_t)2 * NNODE * 4);
  unsigned* dflags = (unsigned*)(ws + (size_t)3 * NNODE * 4);

  k_detect<<<1, 64, 0, stream>>>(u, v, dflags);
  k_init<<<2048, 256, 0, stream>>>(logit, xs, delta, claim, outX);

  for (int t = 0; t < TSTEPS; ++t) {
    kG<<<NEDGE / 256, 256, 0, stream>>>(u, v, sp, sm, theta, xs, delta,
                                        outKp, outKm, dflags, t);
    if (t < TSTEPS - 1) {
      kA<<<2 * NEDGE / 256, 256, 0, stream>>>(u, v, xs, delta, claim,
                                              outX, dflags, t);
    }
  }

  k_fill<<<(NNODE + 255) / 256, 256, 0, stream>>>(logit, (unsigned*)d_out);
}